// Round 19
// baseline (145.741 us; speedup 1.0000x reference)
//
#include <hip/hip_runtime.h>
#include <math.h>

#define C 64
#define R 32
#define CUTOFF 5.0f
#define PI_F 3.14159265358979323846f

typedef __attribute__((ext_vector_type(8))) short short8b;
typedef __attribute__((ext_vector_type(4))) short short4b;
typedef __attribute__((ext_vector_type(4))) float f32x4;

__device__ __forceinline__ float silu(float x) { return x / (1.0f + __expf(-x)); }

__device__ __forceinline__ unsigned short f2bfu(float x) {
  unsigned u = __builtin_bit_cast(unsigned, x);
  u += 0x7FFF + ((u >> 16) & 1);           // round-to-nearest-even
  return (unsigned short)(u >> 16);
}
__device__ __forceinline__ float bflo(unsigned u) {
  return __builtin_bit_cast(float, u << 16);
}
__device__ __forceinline__ float bfhi(unsigned u) {
  return __builtin_bit_cast(float, u & 0xffff0000u);
}
__device__ __forceinline__ float bfu2f(unsigned short s) {
  return __builtin_bit_cast(float, (unsigned)s << 16);
}
__device__ __forceinline__ unsigned pk2c(float a, float b) {
  unsigned r;
  asm("v_cvt_pk_bf16_f32 %0, %1, %2" : "=v"(r) : "v"(a), "v"(b));
  return r;                                 // lo = bf16(a), hi = bf16(b), RNE
}

#define DOT2(ACC, A, B) \
  asm("v_dot2_f32_bf16 %0, %1, %2, %0" : "+v"(ACC) : "v"(A), "v"(B))

// ---------------------------------------------------------------------------
// Fused: histogram + MFMA weight prep + Wt k-pair bf16 packing (WP[6][32][64]).
// W3 of the MLP is column-permuted to plane order n' = (n%3)*64+n/3.
// ---------------------------------------------------------------------------
__global__ __launch_bounds__(256) void k_misc(
    const int* __restrict__ ei, int* __restrict__ deg, int E, int histB,
    const float* __restrict__ W1, const float* __restrict__ W2,
    const float* __restrict__ W3, const float* __restrict__ Wt,
    unsigned short* __restrict__ Wf, unsigned* __restrict__ WP) {
  const int bid = blockIdx.x;
  if (bid < histB) {
    int e = bid * 256 + threadIdx.x;
    if (e < E) atomicAdd(&deg[ei[e]], 1);
    return;
  }
  if (bid < histB + 136) {
    int id = (bid - histB) * 256 + threadIdx.x;
    if (id >= 34816) return;
    int i, l, t;
    if (id < 2048) {
      i = id & 7; l = (id >> 3) & 63; t = id >> 9;
      int nt = t % 4, ks = t / 4;
      int k = ks * 32 + ((l >> 4) << 2) + (i & 3) + ((i >> 2) << 4);
      int n = nt * 16 + (l & 15);
      Wf[id] = f2bfu(W1[(size_t)k * 64 + n]);
    } else if (id < 10240) {
      int id2 = id - 2048;
      i = id2 & 7; l = (id2 >> 3) & 63; t = id2 >> 9;
      int nt = t % 8, ks = t / 8;
      int k = ks * 32 + ((l >> 4) << 2) + (i & 3) + ((i >> 2) << 4);
      int n = nt * 16 + (l & 15);
      Wf[id] = f2bfu(W2[(size_t)k * 128 + n]);
    } else {
      int id2 = id - 10240;
      i = id2 & 7; l = (id2 >> 3) & 63; t = id2 >> 9;
      int nt = t % 12, ks = t / 12;
      int k = ks * 32 + ((l >> 4) << 2) + (i & 3) + ((i >> 2) << 4);
      int nperm = nt * 16 + (l & 15);            // plane order
      int norig = (nperm & 63) * 3 + (nperm >> 6);
      Wf[id] = f2bfu(W3[(size_t)k * 192 + norig]);
    }
    return;
  }
  // ---- Wt k-pair packing: WP[m][kp][c] = (Wt[m][2kp][c], Wt[m][2kp+1][c]) ----
  int id = (bid - histB - 136) * 256 + threadIdx.x;
  if (id >= 6 * 2048) return;
  int m = id >> 11, r2 = id & 2047;
  int kp = r2 >> 6, c = r2 & 63;
  const float* Wm = Wt + (size_t)m * 4096;
  WP[id] = pk2c(Wm[(2 * kp) * 64 + c], Wm[(2 * kp + 1) * 64 + c]);
}

// ---------------------------------------------------------------------------
// CSR build (scan only; fill fused into the mega kernel).
// ---------------------------------------------------------------------------
__global__ __launch_bounds__(1024) void k_scan(const int* __restrict__ deg,
                                               int* __restrict__ off,
                                               int* __restrict__ cur, int N) {
  __shared__ int sums[1024];
  const int t = threadIdx.x;
  const int L = (N + 1023) / 1024;
  const int base = t * L;
  int s = 0;
  for (int j = 0; j < L; j++) if (base + j < N) s += deg[base + j];
  sums[t] = s;
  __syncthreads();
  for (int d = 1; d < 1024; d <<= 1) {
    int v = (t >= d) ? sums[t - d] : 0;
    __syncthreads();
    sums[t] += v;
    __syncthreads();
  }
  int run = (t > 0) ? sums[t - 1] : 0;
  for (int j = 0; j < L; j++) {
    int i = base + j;
    if (i < N) { off[i] = run; run += deg[i]; cur[i] = 0; }
  }
  if (t == 1023) off[N] = sums[1023];
}

// ---------------------------------------------------------------------------
// MEGA dispatch: blocks [0,mlpPersist) = PERSISTENT edge-MLP blocks (weights
// loaded once into registers, grid-stride over 32-edge tiles); blocks
// [mlpPersist,..) = node prep with DOT2 channel-mix. bf16 node features,
// fa split (f0,f2)+(f1), Xn bf16.
// ---------------------------------------------------------------------------
__global__ __launch_bounds__(256) void k_mega(
    const float* __restrict__ ew, const float* __restrict__ ea,
    const int* __restrict__ ei,
    const float* __restrict__ b1, const float* __restrict__ b2,
    const float* __restrict__ b3, const unsigned short* __restrict__ Wf,
    const unsigned* __restrict__ WP,
    const int* __restrict__ off, int* __restrict__ cur,
    int* __restrict__ dlist, unsigned* __restrict__ fa02,
    unsigned short* __restrict__ fb1, int E, int mlpPersist,
    const float* __restrict__ X,
    unsigned short* __restrict__ Xn, unsigned* __restrict__ nfh, int N) {
  __shared__ __align__(16) char smem[16384];
  __shared__ float cws[32];
  __shared__ int posB[32];
  const int tid = threadIdx.x;

  if ((int)blockIdx.x >= mlpPersist) {
    // ---- node prep ----
    unsigned (*comps2)[32][12] = (unsigned (*)[32][12])smem;  // 6144 B
    const int ln = tid >> 6;
    const int c  = tid & 63;
    const int node = ((int)blockIdx.x - mlpPersist) * 4 + ln;
    float cp[10];
    if (node < N) {
      const float* xp = X + ((size_t)node * C + c) * 9;
      float x[9]; float nrm = 0.f;
#pragma unroll
      for (int j = 0; j < 9; j++) { x[j] = xp[j]; nrm += x[j] * x[j]; }
      const float inv = 1.0f / (nrm + 1.0f);
#pragma unroll
      for (int j = 0; j < 9; j++) x[j] *= inv;
      unsigned short* xnp = Xn + (size_t)node * 576 + c;
#pragma unroll
      for (int j = 0; j < 9; j++) xnp[j * 64] = f2bfu(x[j]);
      const float tr3 = (x[0] + x[4] + x[8]) * (1.f / 3.f);
      cp[0] = tr3;
      cp[1] = 0.5f * (x[1] - x[3]);
      cp[2] = 0.5f * (x[2] - x[6]);
      cp[3] = 0.5f * (x[5] - x[7]);
      cp[4] = x[0] - tr3;
      cp[5] = x[4] - tr3;
      cp[6] = x[8] - tr3;
      cp[7] = 0.5f * (x[1] + x[3]);
      cp[8] = 0.5f * (x[2] + x[6]);
      cp[9] = 0.5f * (x[5] + x[7]);
      // pair-pack over channel pairs (lane c with c^1) -> bf16 dwords
#pragma unroll
      for (int j = 0; j < 10; j++) {
        float pr = __shfl_xor(cp[j], 1, 64);
        float lo = (c & 1) ? pr : cp[j];
        float hi = (c & 1) ? cp[j] : pr;
        if (!(c & 1)) comps2[ln][c >> 1][j] = pk2c(lo, hi);
      }
    }
    __syncthreads();
    if (node < N) {
      const unsigned* WP0 = WP;
      const unsigned* WP1 = WP + 2048;
      const unsigned* WP2 = WP + 4096;
      float o[10];
#pragma unroll
      for (int j = 0; j < 10; j++) o[j] = 0.f;
      for (int kp = 0; kp < 32; kp++) {
        unsigned w0 = WP0[kp * 64 + c];
        unsigned w1 = WP1[kp * 64 + c];
        unsigned w2 = WP2[kp * 64 + c];
        const unsigned* cr = comps2[ln][kp];
        uint4 q0 = *(const uint4*)cr;
        uint4 q1 = *(const uint4*)(cr + 4);
        uint2 q2 = *(const uint2*)(cr + 8);
        DOT2(o[0], w0, q0.x);
        DOT2(o[1], w1, q0.y); DOT2(o[2], w1, q0.z); DOT2(o[3], w1, q0.w);
        DOT2(o[4], w2, q1.x); DOT2(o[5], w2, q1.y); DOT2(o[6], w2, q1.z);
        DOT2(o[7], w2, q1.w); DOT2(o[8], w2, q2.x); DOT2(o[9], w2, q2.y);
      }
      // dot2-order packing: (iv,s00)(iv,s11)(iv,s22)(a0,s01)(a1,s02)(a2,s12)
      unsigned* hp = nfh + (size_t)node * 384 + c * 6;
      *(uint2*)hp       = make_uint2(pk2c(o[0], o[4]), pk2c(o[0], o[5]));
      *(uint2*)(hp + 2) = make_uint2(pk2c(o[0], o[6]), pk2c(o[1], o[7]));
      *(uint2*)(hp + 4) = make_uint2(pk2c(o[2], o[8]), pk2c(o[3], o[9]));
    }
    return;
  }

  // ---- persistent edge MLP ----
  unsigned short (*attrB)[40]  = (unsigned short (*)[40])smem;            // 2560 B
  unsigned short (*h1B)[76]    = (unsigned short (*)[76])(smem + 2560);   // 4864 B
  unsigned short (*h2B)[140]   = (unsigned short (*)[140])(smem + 7424);  // 8960 B

  const int wv = tid >> 6, l = tid & 63;
  const int g = l >> 4, r = l & 15;
  const short8b* WfL1 = (const short8b*)Wf;
  const short8b* WfL2 = WfL1 + 256;
  const short8b* WfL3 = WfL1 + 1280;

  // load ALL weight fragments once (persist in registers across tiles)
  short8b w1f = WfL1[wv * 64 + l];
  short8b w2f[2][2];
#pragma unroll
  for (int ks = 0; ks < 2; ks++)
#pragma unroll
    for (int j = 0; j < 2; j++)
      w2f[ks][j] = WfL2[(ks * 8 + 2 * wv + j) * 64 + l];
  short8b w3f[4][3];
#pragma unroll
  for (int ks = 0; ks < 4; ks++)
#pragma unroll
    for (int j = 0; j < 3; j++)
      w3f[ks][j] = WfL3[(ks * 12 + j * 4 + wv) * 64 + l];
  float4 bb1v = *(const float4*)(b1 + wv * 16 + g * 4);
  f32x4 binit = (f32x4){bb1v.x, bb1v.y, bb1v.z, bb1v.w};
  float4 bA = *(const float4*)(b2 + (2 * wv) * 16 + g * 4);
  float4 bB = *(const float4*)(b2 + (2 * wv + 1) * 16 + g * 4);
  f32x4 biA = (f32x4){bA.x, bA.y, bA.z, bA.w};
  f32x4 biB = (f32x4){bB.x, bB.y, bB.z, bB.w};
  const int ch = wv * 16 + r;
  float bb0 = b3[ch * 3 + 0];
  float bb1 = b3[ch * 3 + 1];
  float bb2v = b3[ch * 3 + 2];

  const int nTiles = (E + 31) / 32;
  for (int tp = blockIdx.x; tp < nTiles; tp += mlpPersist) {
    const int e0 = tp * 32;

    { // stage edge_attr: 8 lanes/edge, 1 float4 each -> bf16 LDS rows
      int el = tid >> 3, q = tid & 7;
      int e = e0 + el;
      uint2 pk = make_uint2(0, 0);
      if (e < E) {
        const float4 x0 = *(const float4*)(ea + (size_t)e * R + q * 4);
        pk.x = pk2c(x0.x, x0.y); pk.y = pk2c(x0.z, x0.w);
      }
      *(uint2*)&attrB[el][q * 4] = pk;
    }
    if (tid < 32) {
      int e = e0 + tid;
      if (e < E) {
        float wgt = ew[e];
        float cc = 0.5f * (cosf(wgt * (PI_F / CUTOFF)) + 1.0f);
        cws[tid] = (wgt < CUTOFF) ? cc : 0.f;
        int s = ei[e];
        int d = ei[E + e];
        int pos = off[s] + atomicAdd(&cur[s], 1);
        posB[tid] = pos;
        dlist[pos] = d;
      } else {
        cws[tid] = 0.f;
        posB[tid] = 0;
      }
    }
    __syncthreads();

    // ---- layer 1 (swapped): wave w computes outcols [16w, 16w+16) ----
#pragma unroll
    for (int t = 0; t < 2; t++) {
      const unsigned short* arow = &attrB[t * 16 + r][0];
      short4b lo = *(const short4b*)(arow + g * 4);
      short4b hi = *(const short4b*)(arow + 16 + g * 4);
      short8b efrag = __builtin_shufflevector(lo, hi, 0, 1, 2, 3, 4, 5, 6, 7);
      f32x4 acc = binit;
      acc = __builtin_amdgcn_mfma_f32_16x16x32_bf16(w1f, efrag, acc, 0, 0, 0);
      uint2 v = make_uint2(pk2c(silu(acc[0]), silu(acc[1])),
                           pk2c(silu(acc[2]), silu(acc[3])));
      *(uint2*)&h1B[t * 16 + r][wv * 16 + g * 4] = v;
    }
    __syncthreads();

    // ---- layer 2 (swapped): wave w computes outcols [32w, 32w+32) ----
#pragma unroll
    for (int t = 0; t < 2; t++) {
      f32x4 aA = biA, aB = biB;
      const unsigned short* hrow = &h1B[t * 16 + r][0];
#pragma unroll
      for (int ks = 0; ks < 2; ks++) {
        short4b lo = *(const short4b*)(hrow + ks * 32 + g * 4);
        short4b hi = *(const short4b*)(hrow + ks * 32 + 16 + g * 4);
        short8b efrag = __builtin_shufflevector(lo, hi, 0, 1, 2, 3, 4, 5, 6, 7);
        aA = __builtin_amdgcn_mfma_f32_16x16x32_bf16(w2f[ks][0], efrag, aA, 0, 0, 0);
        aB = __builtin_amdgcn_mfma_f32_16x16x32_bf16(w2f[ks][1], efrag, aB, 0, 0, 0);
      }
      uint2 vA = make_uint2(pk2c(silu(aA[0]), silu(aA[1])),
                            pk2c(silu(aA[2]), silu(aA[3])));
      uint2 vB = make_uint2(pk2c(silu(aB[0]), silu(aB[1])),
                            pk2c(silu(aB[2]), silu(aB[3])));
      *(uint2*)&h2B[t * 16 + r][(2 * wv) * 16 + g * 4] = vA;
      *(uint2*)&h2B[t * 16 + r][(2 * wv + 1) * 16 + g * 4] = vB;
    }
    __syncthreads();

    // ---- layer 3 (non-swapped, plane-permuted W3): wave w owns channel ch ----
#pragma unroll
    for (int t = 0; t < 2; t++) {
      f32x4 p0v = (f32x4){bb0, bb0, bb0, bb0};
      f32x4 p1v = (f32x4){bb1, bb1, bb1, bb1};
      f32x4 p2v = (f32x4){bb2v, bb2v, bb2v, bb2v};
      const unsigned short* hrow = &h2B[t * 16 + r][0];
#pragma unroll
      for (int ks = 0; ks < 4; ks++) {
        short4b lo = *(const short4b*)(hrow + ks * 32 + g * 4);
        short4b hi = *(const short4b*)(hrow + ks * 32 + 16 + g * 4);
        short8b a = __builtin_shufflevector(lo, hi, 0, 1, 2, 3, 4, 5, 6, 7);
        p0v = __builtin_amdgcn_mfma_f32_16x16x32_bf16(a, w3f[ks][0], p0v, 0, 0, 0);
        p1v = __builtin_amdgcn_mfma_f32_16x16x32_bf16(a, w3f[ks][1], p1v, 0, 0, 0);
        p2v = __builtin_amdgcn_mfma_f32_16x16x32_bf16(a, w3f[ks][2], p2v, 0, 0, 0);
      }
#pragma unroll
      for (int reg = 0; reg < 4; reg++) {
        int el = t * 16 + g * 4 + reg;
        int e = e0 + el;
        float cw = cws[el];
        float s0 = silu(p0v[reg]) * cw;
        float s1 = silu(p1v[reg]) * cw;
        float s2 = silu(p2v[reg]) * cw;
        if (e < E) {
          size_t pos = (size_t)posB[el];
          fa02[pos * 64 + ch] = pk2c(s0, s2);   // (f0, f2)
          fb1[pos * 64 + ch]  = f2bfu(s1);      // f1
        }
      }
    }
    __syncthreads();   // protect attrB/cws/posB before next tile's staging
  }
}

// ---------------------------------------------------------------------------
// Fused gather + output: ONE NODE PER BLOCK, 4-way wave edge-split,
// 4-slot round-robin prefetch, 9x v_dot2_f32_bf16 per edge; epilogue Y from
// bf16 nfh; channel-mix via dot2 (WP[3..5]); Xn bf16.
// ---------------------------------------------------------------------------
struct Slot { unsigned f02; unsigned short f1; uint2 q0, q1, q2; };

__device__ __forceinline__ void load_slot(
    Slot& s, int ii, int t0, const int* __restrict__ dlist,
    const unsigned* __restrict__ fa02, const unsigned short* __restrict__ fb1,
    const unsigned* __restrict__ nfh, int c) {
  if (ii < t0) {
    int d = dlist[ii];
    s.f02 = fa02[(size_t)ii * 64 + c];
    s.f1  = fb1[(size_t)ii * 64 + c];
    const uint2* np = (const uint2*)(nfh + (size_t)d * 384 + c * 6);
    s.q0 = np[0]; s.q1 = np[1]; s.q2 = np[2];
  } else {
    s.f02 = 0; s.f1 = 0;
    s.q0 = make_uint2(0, 0); s.q1 = s.q0; s.q2 = s.q0;
  }
}

__device__ __forceinline__ void acc_slot(const Slot& s, float* m) {
  unsigned F02 = s.f02;                              // (f0, f2)
  unsigned F12 = (s.f02 & 0xffff0000u) | s.f1;       // (f1, f2)
  unsigned F12m = F12 ^ 0x8000u;                     // (-f1, f2)
  DOT2(m[0], F02, s.q0.x);   // f0*iv + f2*s00
  DOT2(m[4], F02, s.q0.y);   // f0*iv + f2*s11
  DOT2(m[8], F02, s.q1.x);   // f0*iv + f2*s22
  DOT2(m[1], F12,  s.q1.y);  // f1*a0 + f2*s01
  DOT2(m[3], F12m, s.q1.y);  // -f1*a0 + f2*s01
  DOT2(m[2], F12,  s.q2.x);  // f1*a1 + f2*s02
  DOT2(m[6], F12m, s.q2.x);
  DOT2(m[5], F12,  s.q2.y);  // f1*a2 + f2*s12
  DOT2(m[7], F12m, s.q2.y);
}

__global__ __launch_bounds__(256) void k_gather_out(
    const int* __restrict__ dlist, const int* __restrict__ off,
    const unsigned* __restrict__ fa02, const unsigned short* __restrict__ fb1,
    const unsigned* __restrict__ nfh, const unsigned short* __restrict__ Xn,
    const unsigned* __restrict__ WP, float* __restrict__ out, int N) {
  const int wv = threadIdx.x >> 6;
  const int c  = threadIdx.x & 63;
  const int node = blockIdx.x;
  __shared__ float part[3][64][10];
  __shared__ __align__(16) unsigned comps2[32][12];

  float m[9];
#pragma unroll
  for (int j = 0; j < 9; j++) m[j] = 0.f;

  {
    const int t0 = off[node + 1];
    int p = off[node] + wv;
    if (p < t0) {
      Slot s0, s1, s2, s3;
      load_slot(s0, p,      t0, dlist, fa02, fb1, nfh, c);
      load_slot(s1, p + 4,  t0, dlist, fa02, fb1, nfh, c);
      load_slot(s2, p + 8,  t0, dlist, fa02, fb1, nfh, c);
      load_slot(s3, p + 12, t0, dlist, fa02, fb1, nfh, c);
      p += 16;
      while (p < t0) {
        acc_slot(s0, m); load_slot(s0, p,      t0, dlist, fa02, fb1, nfh, c);
        acc_slot(s1, m); load_slot(s1, p + 4,  t0, dlist, fa02, fb1, nfh, c);
        acc_slot(s2, m); load_slot(s2, p + 8,  t0, dlist, fa02, fb1, nfh, c);
        acc_slot(s3, m); load_slot(s3, p + 12, t0, dlist, fa02, fb1, nfh, c);
        p += 16;
      }
      acc_slot(s0, m); acc_slot(s1, m); acc_slot(s2, m); acc_slot(s3, m);
    }
  }
  if (wv > 0) {
#pragma unroll
    for (int j = 0; j < 9; j++) part[wv - 1][c][j] = m[j];
  }
  __syncthreads();

  if (wv == 0) {
#pragma unroll
    for (int j = 0; j < 9; j++)
      m[j] += part[0][c][j] + part[1][c][j] + part[2][c][j];
    // own-node comps from bf16 nfh: (iv,s00)(iv,s11)(iv,s22)(a0,s01)(a1,s02)(a2,s12)
    const uint2* np = (const uint2*)(nfh + (size_t)node * 384 + c * 6);
    uint2 q0 = np[0], q1 = np[1], q2 = np[2];
    float iv  = bflo(q0.x), s00 = bfhi(q0.x), s11 = bfhi(q0.y);
    float s22 = bfhi(q1.x), a0 = bflo(q1.y), s01 = bfhi(q1.y);
    float a1 = bflo(q2.x), s02 = bfhi(q2.x);
    float a2 = bflo(q2.y), s12 = bfhi(q2.y);
    float Y[9] = { iv + s00, a0 + s01, a1 + s02,
                   s01 - a0, iv + s11, a2 + s12,
                   s02 - a1, s12 - a2, iv + s22 };
    float M[9];
#pragma unroll
    for (int i2 = 0; i2 < 3; i2++)
#pragma unroll
      for (int j2 = 0; j2 < 3; j2++) {
        float acc = 0.f;
#pragma unroll
        for (int k2 = 0; k2 < 3; k2++)
          acc += m[i2 * 3 + k2] * Y[k2 * 3 + j2] + Y[i2 * 3 + k2] * m[k2 * 3 + j2];
        M[i2 * 3 + j2] = acc;
      }
    float nrm = 0.f;
#pragma unroll
    for (int j = 0; j < 9; j++) nrm += M[j] * M[j];
    const float inv = 1.0f / (nrm + 1.0f);
    const float tr3 = (M[0] + M[4] + M[8]) * (1.f / 3.f);
    float cp[10];
    cp[0] = tr3 * inv;
    cp[1] = 0.5f * (M[1] - M[3]) * inv;
    cp[2] = 0.5f * (M[2] - M[6]) * inv;
    cp[3] = 0.5f * (M[5] - M[7]) * inv;
    cp[4] = (M[0] - tr3) * inv;
    cp[5] = (M[4] - tr3) * inv;
    cp[6] = (M[8] - tr3) * inv;
    cp[7] = 0.5f * (M[1] + M[3]) * inv;
    cp[8] = 0.5f * (M[2] + M[6]) * inv;
    cp[9] = 0.5f * (M[5] + M[7]) * inv;
    // pair-pack over channel pairs -> bf16 dwords
#pragma unroll
    for (int j = 0; j < 10; j++) {
      float pr = __shfl_xor(cp[j], 1, 64);
      float lo = (c & 1) ? pr : cp[j];
      float hi = (c & 1) ? cp[j] : pr;
      if (!(c & 1)) comps2[c >> 1][j] = pk2c(lo, hi);
    }
  }
  __syncthreads();

  // ---- channel mix with WP[3..5], kp split 4 ways across waves ----
  float o[10];
#pragma unroll
  for (int j = 0; j < 10; j++) o[j] = 0.f;
  {
    const unsigned* WP3 = WP + 3 * 2048;
    const unsigned* WP4 = WP + 4 * 2048;
    const unsigned* WP5 = WP + 5 * 2048;
    for (int kp = wv * 8; kp < wv * 8 + 8; kp++) {
      unsigned w3 = WP3[kp * 64 + c];
      unsigned w4 = WP4[kp * 64 + c];
      unsigned w5 = WP5[kp * 64 + c];
      const unsigned* cr = comps2[kp];
      uint4 q0 = *(const uint4*)cr;
      uint4 q1 = *(const uint4*)(cr + 4);
      uint2 q2 = *(const uint2*)(cr + 8);
      DOT2(o[0], w3, q0.x);
      DOT2(o[1], w4, q0.y); DOT2(o[2], w4, q0.z); DOT2(o[3], w4, q0.w);
      DOT2(o[4], w5, q1.x); DOT2(o[5], w5, q1.y); DOT2(o[6], w5, q1.z);
      DOT2(o[7], w5, q1.w); DOT2(o[8], w5, q2.x); DOT2(o[9], w5, q2.y);
    }
  }
  if (wv > 0) {
#pragma unroll
    for (int j = 0; j < 10; j++) part[wv - 1][c][j] = o[j];
  }
  __syncthreads();
  if (wv == 0) {
#pragma unroll
    for (int j = 0; j < 10; j++)
      o[j] += part[0][c][j] + part[1][c][j] + part[2][c][j];
    float dX[9] = { o[0] + o[4], o[1] + o[7], o[2] + o[8],
                    o[7] - o[1], o[0] + o[5], o[3] + o[9],
                    o[8] - o[2], o[9] - o[3], o[0] + o[6] };
    float dd[9];
#pragma unroll
    for (int i2 = 0; i2 < 3; i2++)
#pragma unroll
      for (int j2 = 0; j2 < 3; j2++) {
        float acc = 0.f;
#pragma unroll
        for (int k2 = 0; k2 < 3; k2++) acc += dX[i2 * 3 + k2] * dX[k2 * 3 + j2];
        dd[i2 * 3 + j2] = acc;
      }
    const unsigned short* xnp = Xn + (size_t)node * 576 + c;
    float* op = out + ((size_t)node * C + c) * 9;
#pragma unroll
    for (int j = 0; j < 9; j++) op[j] = bfu2f(xnp[j * 64]) + dX[j] + dd[j];
  }
}

extern "C" void kernel_launch(void* const* d_in, const int* in_sizes, int n_in,
                              void* d_out, int out_size, void* d_ws, size_t ws_size,
                              hipStream_t stream) {
  const float* X  = (const float*)d_in[0];
  const int*   ei = (const int*)d_in[1];
  const float* ew = (const float*)d_in[2];
  const float* ea = (const float*)d_in[3];
  const float* W1 = (const float*)d_in[4];
  const float* b1 = (const float*)d_in[5];
  const float* W2 = (const float*)d_in[6];
  const float* b2 = (const float*)d_in[7];
  const float* W3 = (const float*)d_in[8];
  const float* b3 = (const float*)d_in[9];
  const float* Wt = (const float*)d_in[10];
  const int N = in_sizes[0] / (C * 9);
  const int E = in_sizes[1] / 2;

  unsigned short* Xn = (unsigned short*)d_ws;                    // [N][9][C] bf16
  unsigned* nfh = (unsigned*)(Xn + (size_t)N * 576);             // [N][C][6]
  unsigned* fa02 = nfh + (size_t)N * 384;                        // [E][64] u32
  unsigned short* fb1 = (unsigned short*)(fa02 + (size_t)E * 64);// [E][64] u16
  unsigned short* Wf = fb1 + (size_t)E * 64;                     // 34816 u16
  unsigned* WP = (unsigned*)(Wf + 34816);                        // [6][32][64]
  int* deg  = (int*)(WP + 6 * 2048);                             // [N]
  int* off  = deg + N;                                           // [N+1]
  int* cur  = off + N + 1;                                       // [N]
  int* dlist = cur + N;                                          // [E]

  const int histB = (E + 255) / 256;
  const int wpB   = (6 * 2048 + 255) / 256;
  const int mlpPersist = 2048;
  const int nodeB = (N + 3) / 4;
  (void)hipMemsetAsync(deg, 0, (size_t)N * sizeof(int), stream);
  k_misc<<<histB + 136 + wpB, 256, 0, stream>>>(ei, deg, E, histB,
                                                W1, W2, W3, Wt, Wf, WP);
  k_scan<<<1, 1024, 0, stream>>>(deg, off, cur, N);
  k_mega<<<mlpPersist + nodeB, 256, 0, stream>>>(ew, ea, ei, b1, b2, b3, Wf, WP,
                                                 off, cur, dlist, fa02, fb1,
                                                 E, mlpPersist, X, Xn, nfh, N);
  k_gather_out<<<N, 256, 0, stream>>>(dlist, off, fa02, fb1, nfh, Xn, WP,
                                      (float*)d_out, N);
}

// Round 20
// 141.170 us; speedup vs baseline: 1.0324x; 1.0324x over previous
//
#include <hip/hip_runtime.h>
#include <math.h>

#define C 64
#define R 32
#define CUTOFF 5.0f
#define PI_F 3.14159265358979323846f

typedef __attribute__((ext_vector_type(8))) short short8b;
typedef __attribute__((ext_vector_type(4))) short short4b;
typedef __attribute__((ext_vector_type(4))) float f32x4;

__device__ __forceinline__ float silu(float x) { return x / (1.0f + __expf(-x)); }

__device__ __forceinline__ unsigned short f2bfu(float x) {
  unsigned u = __builtin_bit_cast(unsigned, x);
  u += 0x7FFF + ((u >> 16) & 1);           // round-to-nearest-even
  return (unsigned short)(u >> 16);
}
__device__ __forceinline__ float bflo(unsigned u) {
  return __builtin_bit_cast(float, u << 16);
}
__device__ __forceinline__ float bfhi(unsigned u) {
  return __builtin_bit_cast(float, u & 0xffff0000u);
}
__device__ __forceinline__ float bfu2f(unsigned short s) {
  return __builtin_bit_cast(float, (unsigned)s << 16);
}
__device__ __forceinline__ unsigned pk2c(float a, float b) {
  unsigned r;
  asm("v_cvt_pk_bf16_f32 %0, %1, %2" : "=v"(r) : "v"(a), "v"(b));
  return r;                                 // lo = bf16(a), hi = bf16(b), RNE
}

#define DOT2(ACC, A, B) \
  asm("v_dot2_f32_bf16 %0, %1, %2, %0" : "+v"(ACC) : "v"(A), "v"(B))

// ---------------------------------------------------------------------------
// Fused: histogram + MFMA weight prep + Wt k-pair bf16 packing (WP[6][32][64]).
// W3 of the MLP is column-permuted to plane order n' = (n%3)*64+n/3.
// ---------------------------------------------------------------------------
__global__ __launch_bounds__(256) void k_misc(
    const int* __restrict__ ei, int* __restrict__ deg, int E, int histB,
    const float* __restrict__ W1, const float* __restrict__ W2,
    const float* __restrict__ W3, const float* __restrict__ Wt,
    unsigned short* __restrict__ Wf, unsigned* __restrict__ WP) {
  const int bid = blockIdx.x;
  if (bid < histB) {
    int e = bid * 256 + threadIdx.x;
    if (e < E) atomicAdd(&deg[ei[e]], 1);
    return;
  }
  if (bid < histB + 136) {
    int id = (bid - histB) * 256 + threadIdx.x;
    if (id >= 34816) return;
    int i, l, t;
    if (id < 2048) {
      i = id & 7; l = (id >> 3) & 63; t = id >> 9;
      int nt = t % 4, ks = t / 4;
      int k = ks * 32 + ((l >> 4) << 2) + (i & 3) + ((i >> 2) << 4);
      int n = nt * 16 + (l & 15);
      Wf[id] = f2bfu(W1[(size_t)k * 64 + n]);
    } else if (id < 10240) {
      int id2 = id - 2048;
      i = id2 & 7; l = (id2 >> 3) & 63; t = id2 >> 9;
      int nt = t % 8, ks = t / 8;
      int k = ks * 32 + ((l >> 4) << 2) + (i & 3) + ((i >> 2) << 4);
      int n = nt * 16 + (l & 15);
      Wf[id] = f2bfu(W2[(size_t)k * 128 + n]);
    } else {
      int id2 = id - 10240;
      i = id2 & 7; l = (id2 >> 3) & 63; t = id2 >> 9;
      int nt = t % 12, ks = t / 12;
      int k = ks * 32 + ((l >> 4) << 2) + (i & 3) + ((i >> 2) << 4);
      int nperm = nt * 16 + (l & 15);            // plane order
      int norig = (nperm & 63) * 3 + (nperm >> 6);
      Wf[id] = f2bfu(W3[(size_t)k * 192 + norig]);
    }
    return;
  }
  // ---- Wt k-pair packing: WP[m][kp][c] = (Wt[m][2kp][c], Wt[m][2kp+1][c]) ----
  int id = (bid - histB - 136) * 256 + threadIdx.x;
  if (id >= 6 * 2048) return;
  int m = id >> 11, r2 = id & 2047;
  int kp = r2 >> 6, c = r2 & 63;
  const float* Wm = Wt + (size_t)m * 4096;
  WP[id] = pk2c(Wm[(2 * kp) * 64 + c], Wm[(2 * kp + 1) * 64 + c]);
}

// ---------------------------------------------------------------------------
// CSR build (scan only; fill fused into the mega kernel).
// ---------------------------------------------------------------------------
__global__ __launch_bounds__(1024) void k_scan(const int* __restrict__ deg,
                                               int* __restrict__ off,
                                               int* __restrict__ cur, int N) {
  __shared__ int sums[1024];
  const int t = threadIdx.x;
  const int L = (N + 1023) / 1024;
  const int base = t * L;
  int s = 0;
  for (int j = 0; j < L; j++) if (base + j < N) s += deg[base + j];
  sums[t] = s;
  __syncthreads();
  for (int d = 1; d < 1024; d <<= 1) {
    int v = (t >= d) ? sums[t - d] : 0;
    __syncthreads();
    sums[t] += v;
    __syncthreads();
  }
  int run = (t > 0) ? sums[t - 1] : 0;
  for (int j = 0; j < L; j++) {
    int i = base + j;
    if (i < N) { off[i] = run; run += deg[i]; cur[i] = 0; }
  }
  if (t == 1023) off[N] = sums[1023];
}

// ---------------------------------------------------------------------------
// MEGA dispatch: blocks [0,mlpB) = edge MLP (32-edge tiles, MFMA bf16,
// swapped-operand, in-kernel CSR fill); blocks [mlpB,..) = node prep with
// DOT2 channel-mix. Node features bf16-only (nfh); Xn stored bf16.
// fa split: fa02[p][64] dword (f0,f2) + fb1[p][64] ushort f1 (6 B/channel).
// ---------------------------------------------------------------------------
__global__ __launch_bounds__(256) void k_mega(
    const float* __restrict__ ew, const float* __restrict__ ea,
    const int* __restrict__ ei,
    const float* __restrict__ b1, const float* __restrict__ b2,
    const float* __restrict__ b3, const unsigned short* __restrict__ Wf,
    const unsigned* __restrict__ WP,
    const int* __restrict__ off, int* __restrict__ cur,
    int* __restrict__ dlist, unsigned* __restrict__ fa02,
    unsigned short* __restrict__ fb1, int E, int mlpB,
    const float* __restrict__ X,
    unsigned short* __restrict__ Xn, unsigned* __restrict__ nfh, int N) {
  __shared__ __align__(16) char smem[16384];
  __shared__ float cws[32];
  __shared__ int posB[32];
  const int tid = threadIdx.x;

  if ((int)blockIdx.x >= mlpB) {
    // ---- node prep ----
    unsigned (*comps2)[32][12] = (unsigned (*)[32][12])smem;  // 6144 B
    const int ln = tid >> 6;
    const int c  = tid & 63;
    const int node = ((int)blockIdx.x - mlpB) * 4 + ln;
    float cp[10];
    if (node < N) {
      const float* xp = X + ((size_t)node * C + c) * 9;
      float x[9]; float nrm = 0.f;
#pragma unroll
      for (int j = 0; j < 9; j++) { x[j] = xp[j]; nrm += x[j] * x[j]; }
      const float inv = 1.0f / (nrm + 1.0f);
#pragma unroll
      for (int j = 0; j < 9; j++) x[j] *= inv;
      unsigned short* xnp = Xn + (size_t)node * 576 + c;
#pragma unroll
      for (int j = 0; j < 9; j++) xnp[j * 64] = f2bfu(x[j]);
      const float tr3 = (x[0] + x[4] + x[8]) * (1.f / 3.f);
      cp[0] = tr3;
      cp[1] = 0.5f * (x[1] - x[3]);
      cp[2] = 0.5f * (x[2] - x[6]);
      cp[3] = 0.5f * (x[5] - x[7]);
      cp[4] = x[0] - tr3;
      cp[5] = x[4] - tr3;
      cp[6] = x[8] - tr3;
      cp[7] = 0.5f * (x[1] + x[3]);
      cp[8] = 0.5f * (x[2] + x[6]);
      cp[9] = 0.5f * (x[5] + x[7]);
      // pair-pack over channel pairs (lane c with c^1) -> bf16 dwords
#pragma unroll
      for (int j = 0; j < 10; j++) {
        float pr = __shfl_xor(cp[j], 1, 64);
        float lo = (c & 1) ? pr : cp[j];
        float hi = (c & 1) ? cp[j] : pr;
        if (!(c & 1)) comps2[ln][c >> 1][j] = pk2c(lo, hi);
      }
    }
    __syncthreads();
    if (node < N) {
      const unsigned* WP0 = WP;
      const unsigned* WP1 = WP + 2048;
      const unsigned* WP2 = WP + 4096;
      float o[10];
#pragma unroll
      for (int j = 0; j < 10; j++) o[j] = 0.f;
      for (int kp = 0; kp < 32; kp++) {
        unsigned w0 = WP0[kp * 64 + c];
        unsigned w1 = WP1[kp * 64 + c];
        unsigned w2 = WP2[kp * 64 + c];
        const unsigned* cr = comps2[ln][kp];
        uint4 q0 = *(const uint4*)cr;
        uint4 q1 = *(const uint4*)(cr + 4);
        uint2 q2 = *(const uint2*)(cr + 8);
        DOT2(o[0], w0, q0.x);
        DOT2(o[1], w1, q0.y); DOT2(o[2], w1, q0.z); DOT2(o[3], w1, q0.w);
        DOT2(o[4], w2, q1.x); DOT2(o[5], w2, q1.y); DOT2(o[6], w2, q1.z);
        DOT2(o[7], w2, q1.w); DOT2(o[8], w2, q2.x); DOT2(o[9], w2, q2.y);
      }
      // dot2-order packing: (iv,s00)(iv,s11)(iv,s22)(a0,s01)(a1,s02)(a2,s12)
      unsigned* hp = nfh + (size_t)node * 384 + c * 6;
      *(uint2*)hp       = make_uint2(pk2c(o[0], o[4]), pk2c(o[0], o[5]));
      *(uint2*)(hp + 2) = make_uint2(pk2c(o[0], o[6]), pk2c(o[1], o[7]));
      *(uint2*)(hp + 4) = make_uint2(pk2c(o[2], o[8]), pk2c(o[3], o[9]));
    }
    return;
  }

  // ---- edge MLP, 32-edge tile ----
  unsigned short (*attrB)[40]  = (unsigned short (*)[40])smem;            // 2560 B
  unsigned short (*h1B)[76]    = (unsigned short (*)[76])(smem + 2560);   // 4864 B
  unsigned short (*h2B)[140]   = (unsigned short (*)[140])(smem + 7424);  // 8960 B
  const int e0 = blockIdx.x * 32;

  { // stage edge_attr: 8 lanes/edge, 1 float4 each -> bf16 LDS rows
    int el = tid >> 3, q = tid & 7;
    int e = e0 + el;
    uint2 pk = make_uint2(0, 0);
    if (e < E) {
      const float4 x0 = *(const float4*)(ea + (size_t)e * R + q * 4);
      pk.x = pk2c(x0.x, x0.y); pk.y = pk2c(x0.z, x0.w);
    }
    *(uint2*)&attrB[el][q * 4] = pk;
  }
  if (tid < 32) {
    int e = e0 + tid;
    if (e < E) {
      float wgt = ew[e];
      float cc = 0.5f * (cosf(wgt * (PI_F / CUTOFF)) + 1.0f);
      cws[tid] = (wgt < CUTOFF) ? cc : 0.f;
      int s = ei[e];
      int d = ei[E + e];
      int pos = off[s] + atomicAdd(&cur[s], 1);
      posB[tid] = pos;
      dlist[pos] = d;
    } else {
      cws[tid] = 0.f;
      posB[tid] = 0;
    }
  }
  __syncthreads();

  const int wv = tid >> 6, l = tid & 63;
  const int g = l >> 4, r = l & 15;
  const short8b* WfL1 = (const short8b*)Wf;
  const short8b* WfL2 = WfL1 + 256;
  const short8b* WfL3 = WfL1 + 1280;

  // ---- layer 1 (swapped): wave w computes outcols [16w, 16w+16) ----
  {
    short8b w1f = WfL1[wv * 64 + l];
    float4 bb = *(const float4*)(b1 + wv * 16 + g * 4);
    f32x4 binit = (f32x4){bb.x, bb.y, bb.z, bb.w};
#pragma unroll
    for (int t = 0; t < 2; t++) {
      const unsigned short* arow = &attrB[t * 16 + r][0];
      short4b lo = *(const short4b*)(arow + g * 4);
      short4b hi = *(const short4b*)(arow + 16 + g * 4);
      short8b efrag = __builtin_shufflevector(lo, hi, 0, 1, 2, 3, 4, 5, 6, 7);
      f32x4 acc = binit;
      acc = __builtin_amdgcn_mfma_f32_16x16x32_bf16(w1f, efrag, acc, 0, 0, 0);
      uint2 v = make_uint2(pk2c(silu(acc[0]), silu(acc[1])),
                           pk2c(silu(acc[2]), silu(acc[3])));
      *(uint2*)&h1B[t * 16 + r][wv * 16 + g * 4] = v;
    }
  }
  __syncthreads();

  // ---- layer 2 (swapped): wave w computes outcols [32w, 32w+32) ----
  {
    short8b w2f[2][2];
#pragma unroll
    for (int ks = 0; ks < 2; ks++)
#pragma unroll
      for (int j = 0; j < 2; j++)
        w2f[ks][j] = WfL2[(ks * 8 + 2 * wv + j) * 64 + l];
    float4 bA = *(const float4*)(b2 + (2 * wv) * 16 + g * 4);
    float4 bB = *(const float4*)(b2 + (2 * wv + 1) * 16 + g * 4);
    f32x4 biA = (f32x4){bA.x, bA.y, bA.z, bA.w};
    f32x4 biB = (f32x4){bB.x, bB.y, bB.z, bB.w};
#pragma unroll
    for (int t = 0; t < 2; t++) {
      f32x4 aA = biA, aB = biB;
      const unsigned short* hrow = &h1B[t * 16 + r][0];
#pragma unroll
      for (int ks = 0; ks < 2; ks++) {
        short4b lo = *(const short4b*)(hrow + ks * 32 + g * 4);
        short4b hi = *(const short4b*)(hrow + ks * 32 + 16 + g * 4);
        short8b efrag = __builtin_shufflevector(lo, hi, 0, 1, 2, 3, 4, 5, 6, 7);
        aA = __builtin_amdgcn_mfma_f32_16x16x32_bf16(w2f[ks][0], efrag, aA, 0, 0, 0);
        aB = __builtin_amdgcn_mfma_f32_16x16x32_bf16(w2f[ks][1], efrag, aB, 0, 0, 0);
      }
      uint2 vA = make_uint2(pk2c(silu(aA[0]), silu(aA[1])),
                            pk2c(silu(aA[2]), silu(aA[3])));
      uint2 vB = make_uint2(pk2c(silu(aB[0]), silu(aB[1])),
                            pk2c(silu(aB[2]), silu(aB[3])));
      *(uint2*)&h2B[t * 16 + r][(2 * wv) * 16 + g * 4] = vA;
      *(uint2*)&h2B[t * 16 + r][(2 * wv + 1) * 16 + g * 4] = vB;
    }
  }
  __syncthreads();

  // ---- layer 3 (non-swapped, plane-permuted W3): wave w owns channel
  //      ch = 16w + r across planes j=0,1,2 (n-tiles {w, 4+w, 8+w}) ----
  {
    short8b w3f[4][3];
#pragma unroll
    for (int ks = 0; ks < 4; ks++)
#pragma unroll
      for (int j = 0; j < 3; j++)
        w3f[ks][j] = WfL3[(ks * 12 + j * 4 + wv) * 64 + l];
    const int ch = wv * 16 + r;
    float bb0 = b3[ch * 3 + 0];
    float bb1 = b3[ch * 3 + 1];
    float bb2v = b3[ch * 3 + 2];
#pragma unroll
    for (int t = 0; t < 2; t++) {
      f32x4 p0v = (f32x4){bb0, bb0, bb0, bb0};
      f32x4 p1v = (f32x4){bb1, bb1, bb1, bb1};
      f32x4 p2v = (f32x4){bb2v, bb2v, bb2v, bb2v};
      const unsigned short* hrow = &h2B[t * 16 + r][0];
#pragma unroll
      for (int ks = 0; ks < 4; ks++) {
        short4b lo = *(const short4b*)(hrow + ks * 32 + g * 4);
        short4b hi = *(const short4b*)(hrow + ks * 32 + 16 + g * 4);
        short8b a = __builtin_shufflevector(lo, hi, 0, 1, 2, 3, 4, 5, 6, 7);
        p0v = __builtin_amdgcn_mfma_f32_16x16x32_bf16(a, w3f[ks][0], p0v, 0, 0, 0);
        p1v = __builtin_amdgcn_mfma_f32_16x16x32_bf16(a, w3f[ks][1], p1v, 0, 0, 0);
        p2v = __builtin_amdgcn_mfma_f32_16x16x32_bf16(a, w3f[ks][2], p2v, 0, 0, 0);
      }
#pragma unroll
      for (int reg = 0; reg < 4; reg++) {
        int el = t * 16 + g * 4 + reg;
        int e = e0 + el;
        float cw = cws[el];
        float s0 = silu(p0v[reg]) * cw;
        float s1 = silu(p1v[reg]) * cw;
        float s2 = silu(p2v[reg]) * cw;
        if (e < E) {
          size_t pos = (size_t)posB[el];
          fa02[pos * 64 + ch] = pk2c(s0, s2);   // (f0, f2)
          fb1[pos * 64 + ch]  = f2bfu(s1);      // f1
        }
      }
    }
  }
}

// ---------------------------------------------------------------------------
// Fused gather + output: ONE NODE PER BLOCK, 4-way wave edge-split,
// 4-slot round-robin prefetch, 9x v_dot2_f32_bf16 per edge; epilogue Y from
// bf16 nfh; channel-mix via dot2 (WP[3..5]); Xn bf16.
// ---------------------------------------------------------------------------
struct Slot { unsigned f02; unsigned short f1; uint2 q0, q1, q2; };

__device__ __forceinline__ void load_slot(
    Slot& s, int ii, int t0, const int* __restrict__ dlist,
    const unsigned* __restrict__ fa02, const unsigned short* __restrict__ fb1,
    const unsigned* __restrict__ nfh, int c) {
  if (ii < t0) {
    int d = dlist[ii];
    s.f02 = fa02[(size_t)ii * 64 + c];
    s.f1  = fb1[(size_t)ii * 64 + c];
    const uint2* np = (const uint2*)(nfh + (size_t)d * 384 + c * 6);
    s.q0 = np[0]; s.q1 = np[1]; s.q2 = np[2];
  } else {
    s.f02 = 0; s.f1 = 0;
    s.q0 = make_uint2(0, 0); s.q1 = s.q0; s.q2 = s.q0;
  }
}

__device__ __forceinline__ void acc_slot(const Slot& s, float* m) {
  unsigned F02 = s.f02;                              // (f0, f2)
  unsigned F12 = (s.f02 & 0xffff0000u) | s.f1;       // (f1, f2)
  unsigned F12m = F12 ^ 0x8000u;                     // (-f1, f2)
  DOT2(m[0], F02, s.q0.x);   // f0*iv + f2*s00
  DOT2(m[4], F02, s.q0.y);   // f0*iv + f2*s11
  DOT2(m[8], F02, s.q1.x);   // f0*iv + f2*s22
  DOT2(m[1], F12,  s.q1.y);  // f1*a0 + f2*s01
  DOT2(m[3], F12m, s.q1.y);  // -f1*a0 + f2*s01
  DOT2(m[2], F12,  s.q2.x);  // f1*a1 + f2*s02
  DOT2(m[6], F12m, s.q2.x);
  DOT2(m[5], F12,  s.q2.y);  // f1*a2 + f2*s12
  DOT2(m[7], F12m, s.q2.y);
}

__global__ __launch_bounds__(256) void k_gather_out(
    const int* __restrict__ dlist, const int* __restrict__ off,
    const unsigned* __restrict__ fa02, const unsigned short* __restrict__ fb1,
    const unsigned* __restrict__ nfh, const unsigned short* __restrict__ Xn,
    const unsigned* __restrict__ WP, float* __restrict__ out, int N) {
  const int wv = threadIdx.x >> 6;
  const int c  = threadIdx.x & 63;
  const int node = blockIdx.x;
  __shared__ float part[3][64][10];
  __shared__ __align__(16) unsigned comps2[32][12];

  float m[9];
#pragma unroll
  for (int j = 0; j < 9; j++) m[j] = 0.f;

  {
    const int t0 = off[node + 1];
    int p = off[node] + wv;
    if (p < t0) {
      Slot s0, s1, s2, s3;
      load_slot(s0, p,      t0, dlist, fa02, fb1, nfh, c);
      load_slot(s1, p + 4,  t0, dlist, fa02, fb1, nfh, c);
      load_slot(s2, p + 8,  t0, dlist, fa02, fb1, nfh, c);
      load_slot(s3, p + 12, t0, dlist, fa02, fb1, nfh, c);
      p += 16;
      while (p < t0) {
        acc_slot(s0, m); load_slot(s0, p,      t0, dlist, fa02, fb1, nfh, c);
        acc_slot(s1, m); load_slot(s1, p + 4,  t0, dlist, fa02, fb1, nfh, c);
        acc_slot(s2, m); load_slot(s2, p + 8,  t0, dlist, fa02, fb1, nfh, c);
        acc_slot(s3, m); load_slot(s3, p + 12, t0, dlist, fa02, fb1, nfh, c);
        p += 16;
      }
      acc_slot(s0, m); acc_slot(s1, m); acc_slot(s2, m); acc_slot(s3, m);
    }
  }
  if (wv > 0) {
#pragma unroll
    for (int j = 0; j < 9; j++) part[wv - 1][c][j] = m[j];
  }
  __syncthreads();

  if (wv == 0) {
#pragma unroll
    for (int j = 0; j < 9; j++)
      m[j] += part[0][c][j] + part[1][c][j] + part[2][c][j];
    // own-node comps from bf16 nfh: (iv,s00)(iv,s11)(iv,s22)(a0,s01)(a1,s02)(a2,s12)
    const uint2* np = (const uint2*)(nfh + (size_t)node * 384 + c * 6);
    uint2 q0 = np[0], q1 = np[1], q2 = np[2];
    float iv  = bflo(q0.x), s00 = bfhi(q0.x), s11 = bfhi(q0.y);
    float s22 = bfhi(q1.x), a0 = bflo(q1.y), s01 = bfhi(q1.y);
    float a1 = bflo(q2.x), s02 = bfhi(q2.x);
    float a2 = bflo(q2.y), s12 = bfhi(q2.y);
    float Y[9] = { iv + s00, a0 + s01, a1 + s02,
                   s01 - a0, iv + s11, a2 + s12,
                   s02 - a1, s12 - a2, iv + s22 };
    float M[9];
#pragma unroll
    for (int i2 = 0; i2 < 3; i2++)
#pragma unroll
      for (int j2 = 0; j2 < 3; j2++) {
        float acc = 0.f;
#pragma unroll
        for (int k2 = 0; k2 < 3; k2++)
          acc += m[i2 * 3 + k2] * Y[k2 * 3 + j2] + Y[i2 * 3 + k2] * m[k2 * 3 + j2];
        M[i2 * 3 + j2] = acc;
      }
    float nrm = 0.f;
#pragma unroll
    for (int j = 0; j < 9; j++) nrm += M[j] * M[j];
    const float inv = 1.0f / (nrm + 1.0f);
    const float tr3 = (M[0] + M[4] + M[8]) * (1.f / 3.f);
    float cp[10];
    cp[0] = tr3 * inv;
    cp[1] = 0.5f * (M[1] - M[3]) * inv;
    cp[2] = 0.5f * (M[2] - M[6]) * inv;
    cp[3] = 0.5f * (M[5] - M[7]) * inv;
    cp[4] = (M[0] - tr3) * inv;
    cp[5] = (M[4] - tr3) * inv;
    cp[6] = (M[8] - tr3) * inv;
    cp[7] = 0.5f * (M[1] + M[3]) * inv;
    cp[8] = 0.5f * (M[2] + M[6]) * inv;
    cp[9] = 0.5f * (M[5] + M[7]) * inv;
    // pair-pack over channel pairs -> bf16 dwords
#pragma unroll
    for (int j = 0; j < 10; j++) {
      float pr = __shfl_xor(cp[j], 1, 64);
      float lo = (c & 1) ? pr : cp[j];
      float hi = (c & 1) ? cp[j] : pr;
      if (!(c & 1)) comps2[c >> 1][j] = pk2c(lo, hi);
    }
  }
  __syncthreads();

  // ---- channel mix with WP[3..5], kp split 4 ways across waves ----
  float o[10];
#pragma unroll
  for (int j = 0; j < 10; j++) o[j] = 0.f;
  {
    const unsigned* WP3 = WP + 3 * 2048;
    const unsigned* WP4 = WP + 4 * 2048;
    const unsigned* WP5 = WP + 5 * 2048;
    for (int kp = wv * 8; kp < wv * 8 + 8; kp++) {
      unsigned w3 = WP3[kp * 64 + c];
      unsigned w4 = WP4[kp * 64 + c];
      unsigned w5 = WP5[kp * 64 + c];
      const unsigned* cr = comps2[kp];
      uint4 q0 = *(const uint4*)cr;
      uint4 q1 = *(const uint4*)(cr + 4);
      uint2 q2 = *(const uint2*)(cr + 8);
      DOT2(o[0], w3, q0.x);
      DOT2(o[1], w4, q0.y); DOT2(o[2], w4, q0.z); DOT2(o[3], w4, q0.w);
      DOT2(o[4], w5, q1.x); DOT2(o[5], w5, q1.y); DOT2(o[6], w5, q1.z);
      DOT2(o[7], w5, q1.w); DOT2(o[8], w5, q2.x); DOT2(o[9], w5, q2.y);
    }
  }
  if (wv > 0) {
#pragma unroll
    for (int j = 0; j < 10; j++) part[wv - 1][c][j] = o[j];
  }
  __syncthreads();
  if (wv == 0) {
#pragma unroll
    for (int j = 0; j < 10; j++)
      o[j] += part[0][c][j] + part[1][c][j] + part[2][c][j];
    float dX[9] = { o[0] + o[4], o[1] + o[7], o[2] + o[8],
                    o[7] - o[1], o[0] + o[5], o[3] + o[9],
                    o[8] - o[2], o[9] - o[3], o[0] + o[6] };
    float dd[9];
#pragma unroll
    for (int i2 = 0; i2 < 3; i2++)
#pragma unroll
      for (int j2 = 0; j2 < 3; j2++) {
        float acc = 0.f;
#pragma unroll
        for (int k2 = 0; k2 < 3; k2++) acc += dX[i2 * 3 + k2] * dX[k2 * 3 + j2];
        dd[i2 * 3 + j2] = acc;
      }
    const unsigned short* xnp = Xn + (size_t)node * 576 + c;
    float* op = out + ((size_t)node * C + c) * 9;
#pragma unroll
    for (int j = 0; j < 9; j++) op[j] = bfu2f(xnp[j * 64]) + dX[j] + dd[j];
  }
}

extern "C" void kernel_launch(void* const* d_in, const int* in_sizes, int n_in,
                              void* d_out, int out_size, void* d_ws, size_t ws_size,
                              hipStream_t stream) {
  const float* X  = (const float*)d_in[0];
  const int*   ei = (const int*)d_in[1];
  const float* ew = (const float*)d_in[2];
  const float* ea = (const float*)d_in[3];
  const float* W1 = (const float*)d_in[4];
  const float* b1 = (const float*)d_in[5];
  const float* W2 = (const float*)d_in[6];
  const float* b2 = (const float*)d_in[7];
  const float* W3 = (const float*)d_in[8];
  const float* b3 = (const float*)d_in[9];
  const float* Wt = (const float*)d_in[10];
  const int N = in_sizes[0] / (C * 9);
  const int E = in_sizes[1] / 2;

  unsigned short* Xn = (unsigned short*)d_ws;                    // [N][9][C] bf16
  unsigned* nfh = (unsigned*)(Xn + (size_t)N * 576);             // [N][C][6]
  unsigned* fa02 = nfh + (size_t)N * 384;                        // [E][64] u32
  unsigned short* fb1 = (unsigned short*)(fa02 + (size_t)E * 64);// [E][64] u16
  unsigned short* Wf = fb1 + (size_t)E * 64;                     // 34816 u16
  unsigned* WP = (unsigned*)(Wf + 34816);                        // [6][32][64]
  int* deg  = (int*)(WP + 6 * 2048);                             // [N]
  int* off  = deg + N;                                           // [N+1]
  int* cur  = off + N + 1;                                       // [N]
  int* dlist = cur + N;                                          // [E]

  const int histB = (E + 255) / 256;
  const int wpB   = (6 * 2048 + 255) / 256;
  const int mlpB  = (E + 31) / 32;
  const int nodeB = (N + 3) / 4;
  (void)hipMemsetAsync(deg, 0, (size_t)N * sizeof(int), stream);
  k_misc<<<histB + 136 + wpB, 256, 0, stream>>>(ei, deg, E, histB,
                                                W1, W2, W3, Wt, Wf, WP);
  k_scan<<<1, 1024, 0, stream>>>(deg, off, cur, N);
  k_mega<<<mlpB + nodeB, 256, 0, stream>>>(ew, ea, ei, b1, b2, b3, Wf, WP,
                                           off, cur, dlist, fa02, fb1, E, mlpB,
                                           X, Xn, nfh, N);
  k_gather_out<<<N, 256, 0, stream>>>(dlist, off, fa02, fb1, nfh, Xn, WP,
                                      (float*)d_out, N);
}